// Round 4
// baseline (88.210 us; speedup 1.0000x reference)
//
#include <hip/hip_runtime.h>
#include <hip/hip_bf16.h>

#define NROWS 8192      // B*T
#define KDIM  768       // F_IN
#define VSZ   320       // V
#define GSZ   2         // G
#define NCOL  640       // G*V
#define DSZ   128       // D
#define BM    32        // rows per block
#define NBLK  (NROWS / BM)             // 256
#define XQ_TOTAL (NROWS * GSZ * DSZ)   // 2097152
#define MARGIN 1.5f
#define XS_STRIDE 776   // 768 + 8 shorts -> 1552B row stride (4-bank skew, conflict-free)

typedef __attribute__((ext_vector_type(8))) short bf16x8;
typedef __attribute__((ext_vector_type(4))) float f32x4;

static __device__ __forceinline__ short f2bf(float f) {
    union { __hip_bfloat16 h; short s; } u;
    u.h = __float2bfloat16(f);   // round-to-nearest-even
    return u.s;
}

// ---------------- W f32 -> bf16 prep ----------------
__global__ __launch_bounds__(512) void prep_w_k(const float* __restrict__ W,
                                                short* __restrict__ Wb) {
    const size_t i = ((size_t)blockIdx.x * 512 + threadIdx.x) * 8;
    const float4 a = *(const float4*)(W + i);
    const float4 c = *(const float4*)(W + i + 4);
    bf16x8 r;
    r[0] = f2bf(a.x); r[1] = f2bf(a.y); r[2] = f2bf(a.z); r[3] = f2bf(a.w);
    r[4] = f2bf(c.x); r[5] = f2bf(c.y); r[6] = f2bf(c.z); r[7] = f2bf(c.w);
    *(bf16x8*)(Wb + i) = r;
}

#define LOADB(dst, jblk) do {                                                  \
    const int _off = (jblk) * 64;                                              \
    _Pragma("unroll")                                                          \
    for (int n = 0; n < 5; ++n) {                                              \
        dst[n]     = *(const bf16x8*)(Wb + bbase[n] + _off);                   \
        dst[5 + n] = *(const bf16x8*)(Wb + bbase[n] + _off + 32);              \
    } } while (0)

#define DOMFMA(src, jblk) do {                                                 \
    const int _k0 = (jblk) * 64;                                               \
    const bf16x8 a0L = *(const bf16x8*)&xs[l15][_k0 + l4 * 8];                 \
    const bf16x8 a1L = *(const bf16x8*)&xs[16 + l15][_k0 + l4 * 8];            \
    const bf16x8 a0H = *(const bf16x8*)&xs[l15][_k0 + 32 + l4 * 8];            \
    const bf16x8 a1H = *(const bf16x8*)&xs[16 + l15][_k0 + 32 + l4 * 8];       \
    _Pragma("unroll")                                                          \
    for (int n = 0; n < 5; ++n) {                                              \
        acc0[n] = __builtin_amdgcn_mfma_f32_16x16x32_bf16(a0L, src[n], acc0[n], 0, 0, 0); \
        acc1[n] = __builtin_amdgcn_mfma_f32_16x16x32_bf16(a1L, src[n], acc1[n], 0, 0, 0); \
    }                                                                          \
    _Pragma("unroll")                                                          \
    for (int n = 0; n < 5; ++n) {                                              \
        acc0[n] = __builtin_amdgcn_mfma_f32_16x16x32_bf16(a0H, src[5 + n], acc0[n], 0, 0, 0); \
        acc1[n] = __builtin_amdgcn_mfma_f32_16x16x32_bf16(a1H, src[5 + n], acc1[n], 0, 0, 0); \
    } } while (0)

// ---------------- fused bf16-MFMA GEMM + argmax + softmax + fp32 refine + gather ----------------
// grid 256 blocks, 512 threads = 8 waves. Block: rows [bid*32,+32) x all 640 cols.
// Wave w owns cols [80w, 80w+80), all 32 rows. NO global atomics: per-block partials.
__global__ __launch_bounds__(512, 2) void fused_vq_k(
    const float* __restrict__ x, const short* __restrict__ Wb,
    const float* __restrict__ W, const float* __restrict__ b,
    const float* __restrict__ codebook,
    float* __restrict__ partials,   // [NBLK][1280]: counts(640) then probs(640)
    float* __restrict__ xq) {

    __shared__ short xs[BM][XS_STRIDE];      // 49664 B
    __shared__ float pacc[NCOL];
    __shared__ float cnt_f[NCOL];
    __shared__ float wmax[BM][8];
    __shared__ int   warg[BM][8];
    __shared__ float ssum[BM][8];
    __shared__ float rmax_s[BM][2];
    __shared__ int   rarg_s[BM][2];
    __shared__ int   cnt_s[BM][2];
    __shared__ int   list_s[BM][2][16];
    __shared__ int   code_s[BM][2];
    __shared__ int   work_s[64];
    __shared__ int   nwork_s;

    const int tid  = threadIdx.x;
    const int lane = tid & 63;
    const int w    = tid >> 6;       // wave 0..7
    const int g    = w >> 2;         // group
    const int l15  = lane & 15;
    const int l4   = lane >> 4;      // 0..3
    const int row0 = blockIdx.x * BM;

    for (int i = tid; i < NCOL; i += 512) cnt_f[i] = 0.f;
    if (tid < 64) cnt_s[tid >> 1][tid & 1] = 0;
    if (tid == 0) nwork_s = 0;

    // ---- stage full x tile as bf16: 32 rows x 768 k ----
    {
        const int srow = tid >> 4;
        const int sk   = (tid & 15) * 4;
        const float* xp = x + (size_t)(row0 + srow) * KDIM + sk;
#pragma unroll
        for (int t = 0; t < 12; ++t) {
            const float4 v = *(const float4*)(xp + t * 64);
            const short t0 = f2bf(v.x), t1 = f2bf(v.y), t2 = f2bf(v.z), t3 = f2bf(v.w);
            const int lo = (t0 & 0xffff) | (t1 << 16);
            const int hi = (t2 & 0xffff) | (t3 << 16);
            *(int2*)&xs[srow][t * 64 + sk] = make_int2(lo, hi);
        }
    }

    // B fragment bases: col(n) = 80w + 16n + l15, k-offset l4*8
    int bbase[5];
#pragma unroll
    for (int n = 0; n < 5; ++n)
        bbase[n] = (w * 80 + n * 16 + l15) * KDIM + l4 * 8;

    f32x4 acc0[5], acc1[5];
#pragma unroll
    for (int n = 0; n < 5; ++n) {
        acc0[n] = (f32x4){0.f, 0.f, 0.f, 0.f};
        acc1[n] = (f32x4){0.f, 0.f, 0.f, 0.f};
    }

    // depth-2 register pipeline over 12 k-blocks of 64
    bf16x8 b0[10], b1[10], b2[10];
    LOADB(b0, 0);
    LOADB(b1, 1);

    __syncthreads();   // x tile ready

#pragma unroll
    for (int s = 0; s < 12; s += 3) {
        if (s + 2 < 12) LOADB(b2, s + 2);
        DOMFMA(b0, s);
        if (s + 3 < 12) LOADB(b0, s + 3);
        DOMFMA(b1, s + 1);
        if (s + 4 < 12) LOADB(b1, s + 4);
        DOMFMA(b2, s + 2);
    }

    // bias (zeros in this problem, kept exact)
#pragma unroll
    for (int n = 0; n < 5; ++n) {
        const float bv = b[w * 80 + n * 16 + l15];
#pragma unroll
        for (int r = 0; r < 4; ++r) { acc0[n][r] += bv; acc1[n][r] += bv; }
    }

    // E1: wave-local per-row max/argmax over this wave's 80 cols
    float m2[2][4]; int a2[2][4];
#pragma unroll
    for (int h = 0; h < 2; ++h)
#pragma unroll
        for (int r = 0; r < 4; ++r) { m2[h][r] = -3.4e38f; a2[h][r] = 0x7fffffff; }
#pragma unroll
    for (int n = 0; n < 5; ++n) {
        const int col = w * 80 + n * 16 + l15;
#pragma unroll
        for (int r = 0; r < 4; ++r) {
            float v = acc0[n][r];
            if (v > m2[0][r]) { m2[0][r] = v; a2[0][r] = col; }
            v = acc1[n][r];
            if (v > m2[1][r]) { m2[1][r] = v; a2[1][r] = col; }
        }
    }
#pragma unroll
    for (int off = 8; off >= 1; off >>= 1)
#pragma unroll
        for (int h = 0; h < 2; ++h)
#pragma unroll
            for (int r = 0; r < 4; ++r) {
                const float om = __shfl_xor(m2[h][r], off);
                const int   oa = __shfl_xor(a2[h][r], off);
                if (om > m2[h][r] || (om == m2[h][r] && oa < a2[h][r])) { m2[h][r] = om; a2[h][r] = oa; }
            }
    if (l15 == 0)
#pragma unroll
        for (int h = 0; h < 2; ++h)
#pragma unroll
            for (int r = 0; r < 4; ++r) {
                const int row = h * 16 + l4 * 4 + r;
                wmax[row][w] = m2[h][r];
                warg[row][w] = a2[h][r];
            }
    __syncthreads();

    // E2a: combine 4 wave-quarters per group -> row max over 320
    if (tid < 64) {
        const int row = tid >> 1, gg = tid & 1;
        float m = -3.4e38f; int c = 0x7fffffff;
#pragma unroll
        for (int q = 0; q < 4; ++q) {
            const float mq = wmax[row][gg * 4 + q];
            const int   cq = warg[row][gg * 4 + q];
            if (mq > m || (mq == m && cq < c)) { m = mq; c = cq; }
        }
        rmax_s[row][gg] = m;
        rarg_s[row][gg] = c;
    }
    __syncthreads();

    // E2b: candidate scan + exp + denominator partials
    float rm[2][4];
#pragma unroll
    for (int h = 0; h < 2; ++h)
#pragma unroll
        for (int r = 0; r < 4; ++r) rm[h][r] = rmax_s[h * 16 + l4 * 4 + r][g];
    float sden[2][4] = {{0.f,0.f,0.f,0.f},{0.f,0.f,0.f,0.f}};
#pragma unroll
    for (int n = 0; n < 5; ++n) {
        const int col = w * 80 + n * 16 + l15;
#pragma unroll
        for (int h = 0; h < 2; ++h)
#pragma unroll
            for (int r = 0; r < 4; ++r) {
                const float v = h ? acc1[n][r] : acc0[n][r];
                if (v > rm[h][r] - MARGIN) {
                    const int row = h * 16 + l4 * 4 + r;
                    const int idx = atomicAdd(&cnt_s[row][g], 1);
                    if (idx < 16) list_s[row][g][idx] = col;
                }
                const float e = __expf(v - rm[h][r]);
                if (h) acc1[n][r] = e; else acc0[n][r] = e;
                sden[h][r] += e;
            }
    }
#pragma unroll
    for (int off = 8; off >= 1; off >>= 1)
#pragma unroll
        for (int h = 0; h < 2; ++h)
#pragma unroll
            for (int r = 0; r < 4; ++r) sden[h][r] += __shfl_xor(sden[h][r], off);
    if (l15 == 0)
#pragma unroll
        for (int h = 0; h < 2; ++h)
#pragma unroll
            for (int r = 0; r < 4; ++r) ssum[h * 16 + l4 * 4 + r][w] = sden[h][r];
    __syncthreads();

    // E3: single-candidate fast path; multi-candidate -> worklist (no global atomics)
    if (tid < 64) {
        const int row = tid >> 1, gg = tid & 1;
        if (cnt_s[row][gg] <= 1) {
            code_s[row][gg] = rarg_s[row][gg];
        } else {
            const int wi = atomicAdd(&nwork_s, 1);
            work_s[wi] = row * 2 + gg;
        }
    }
    __syncthreads();

    // E5: softmax column sums -> LDS pacc (each col owned by exactly one wave: plain store)
    float inv[2][4];
#pragma unroll
    for (int h = 0; h < 2; ++h)
#pragma unroll
        for (int r = 0; r < 4; ++r) {
            const int row = h * 16 + l4 * 4 + r;
            inv[h][r] = 1.f / (ssum[row][g * 4] + ssum[row][g * 4 + 1] +
                               ssum[row][g * 4 + 2] + ssum[row][g * 4 + 3]);
        }
#pragma unroll
    for (int n = 0; n < 5; ++n) {
        float pc = 0.f;
#pragma unroll
        for (int r = 0; r < 4; ++r)
            pc += acc0[n][r] * inv[0][r] + acc1[n][r] * inv[1][r];
        pc += __shfl_xor(pc, 16);
        pc += __shfl_xor(pc, 32);
        if (l4 == 0) pacc[w * 80 + n * 16 + l15] = pc;
    }

    // E4: fp32-exact refinement, one wave per pending (row,g)
    const int nwork = nwork_s;
    for (int it = w; it < nwork; it += 8) {
        const int rg = work_s[it];
        const int row = rg >> 1, gg = rg & 1;
        const int grow = row0 + row;
        const int nc = min(cnt_s[row][gg], 16);
        float bestv = -3.4e38f; int bestc = 0x7fffffff;
        for (int ci = 0; ci < nc; ++ci) {
            const int col = list_s[row][gg][ci];
            float p = 0.f;
            for (int j = lane; j < KDIM; j += 64)
                p += x[(size_t)grow * KDIM + j] * W[(size_t)col * KDIM + j];
#pragma unroll
            for (int off = 32; off >= 1; off >>= 1) p += __shfl_xor(p, off);
            p += b[col];
            if (p > bestv || (p == bestv && col < bestc)) { bestv = p; bestc = col; }
        }
        if (lane == 0) code_s[row][gg] = bestc;
    }
    __syncthreads();

    // counts histogram in LDS (fast LDS atomics, 64 ops)
    if (tid < 64) {
        const int row = tid >> 1, gg = tid & 1;
        atomicAdd(&cnt_f[code_s[row][gg]], 1.f);
    }

    // E7: gather xq for this block's 32 rows
    {
#pragma unroll
        for (int u = 0; u < 4; ++u) {
            const int f   = tid + u * 512;      // float4 index 0..2047
            const int row = f >> 6;
            const int c   = f & 63;
            const int gg  = c >> 5;
            const int d4  = (c & 31) * 4;
            const int k   = code_s[row][gg];    // global col = g*320+v
            const float4 v = *(const float4*)(codebook + (size_t)k * DSZ + d4);
            *(float4*)(xq + (size_t)(row0 + row) * (GSZ * DSZ) + gg * DSZ + d4) = v;
        }
    }
    __syncthreads();

    // write per-block partials: counts(640) then probs(640), coalesced
    float* myp = partials + (size_t)blockIdx.x * (2 * NCOL);
    for (int i = tid; i < 2 * NCOL; i += 512)
        myp[i] = (i < NCOL) ? cnt_f[i] : pacc[i - NCOL];
}

// ---------------- reduce partials: accf[col] = sum over 256 blocks ----------------
__global__ __launch_bounds__(256) void reduce_k(const float* __restrict__ partials,
                                                float* __restrict__ accf) {
    const int col = blockIdx.x * 256 + threadIdx.x;   // 0..1279
    float s = 0.f;
#pragma unroll 8
    for (int j = 0; j < NBLK; ++j) s += partials[(size_t)j * (2 * NCOL) + col];
    accf[col] = s;
}

// ---------------- perplexities + constant ----------------
__global__ __launch_bounds__(640) void finalize_k(
    const float* __restrict__ counts, const float* __restrict__ probs,
    float* __restrict__ out_scalars) {
    __shared__ float se_c[GSZ], se_p[GSZ];
    const int t = threadIdx.x;
    if (t < GSZ) { se_c[t] = 0.f; se_p[t] = 0.f; }
    __syncthreads();
    const int g = t / VSZ;
    const float hp = counts[t] * (1.f / (float)NROWS);
    const float ap = probs[t]  * (1.f / (float)NROWS);
    float tc = hp * logf(hp + 1e-7f);
    float tp = ap * logf(ap + 1e-7f);
#pragma unroll
    for (int off = 32; off >= 1; off >>= 1) {
        tc += __shfl_xor(tc, off);
        tp += __shfl_xor(tp, off);
    }
    if ((t & 63) == 0) { atomicAdd(&se_c[g], tc); atomicAdd(&se_p[g], tp); }
    __syncthreads();
    if (t == 0) {
        out_scalars[0] = (float)NCOL;
        out_scalars[1] = expf(-se_c[0]) + expf(-se_c[1]);
        out_scalars[2] = expf(-se_p[0]) + expf(-se_p[1]);
    }
}

extern "C" void kernel_launch(void* const* d_in, const int* in_sizes, int n_in,
                              void* d_out, int out_size, void* d_ws, size_t ws_size,
                              hipStream_t stream) {
    const float* x        = (const float*)d_in[0];
    const float* W        = (const float*)d_in[1];
    const float* b        = (const float*)d_in[2];
    const float* codebook = (const float*)d_in[3];
    float* out = (float*)d_out;

    short* Wb       = (short*)d_ws;                                   // 983040 B
    float* partials = (float*)((char*)d_ws + 983040);                 // 256*1280*4 = 1310720 B
    float* accf     = (float*)((char*)d_ws + 983040 + 1310720);       // 1280*4 B

    prep_w_k<<<dim3(120), dim3(512), 0, stream>>>(W, Wb);
    fused_vq_k<<<dim3(NBLK), dim3(512), 0, stream>>>(x, Wb, W, b, codebook,
                                                     partials, out);
    reduce_k<<<dim3(5), dim3(256), 0, stream>>>(partials, accf);
    finalize_k<<<dim3(1), dim3(640), 0, stream>>>(accf, accf + NCOL, out + XQ_TOTAL);
}

// Round 5
// 70.851 us; speedup vs baseline: 1.2450x; 1.2450x over previous
//
#include <hip/hip_runtime.h>
#include <hip/hip_bf16.h>

#define NROWS 8192      // B*T
#define KDIM  768       // F_IN
#define VSZ   320       // V
#define GSZ   2         // G
#define NCOL  640       // G*V
#define DSZ   128       // D
#define BM    32        // rows per block
#define NMT   (NROWS / BM)             // 256 M-tiles
#define NBLK  (NMT * 2)                // 512 blocks (x2 N-halves)
#define NKB   24                       // K blocks of 32
#define XQ_TOTAL (NROWS * GSZ * DSZ)   // 2097152
#define MARGIN 1.5f
#define XS_STRIDE 776   // 768+8 shorts: 16B-aligned rows, 4-word bank skew

typedef __attribute__((ext_vector_type(8))) short bf16x8;
typedef __attribute__((ext_vector_type(4))) float f32x4;

static __device__ __forceinline__ short f2bf(float f) {
    union { __hip_bfloat16 h; short s; } u;
    u.h = __float2bfloat16(f);   // round-to-nearest-even
    return u.s;
}

// ---------------- W f32 -> packed frag-major bf16 ----------------
// Wb layout: frag f = nf*24 + kb  (nf = 16-col group 0..39, kb = 32-k block 0..23).
// Element (f, lane): col = nf*16 + (lane&15), k = kb*32 + (lane>>4)*8, 8 bf16.
// A wave's frag load = 64 lanes x 16B contiguous = 1KB stream.
__global__ __launch_bounds__(512) void prep_w_k(const float* __restrict__ W,
                                                short* __restrict__ Wb) {
    const int idx = blockIdx.x * 512 + threadIdx.x;   // 0..61439
    const int l   = idx & 63;
    const int f   = idx >> 6;        // 0..959
    const int nf  = f / NKB;
    const int kb  = f - nf * NKB;
    const int col = nf * 16 + (l & 15);
    const int k   = kb * 32 + (l >> 4) * 8;
    const float4 a = *(const float4*)(W + (size_t)col * KDIM + k);
    const float4 c = *(const float4*)(W + (size_t)col * KDIM + k + 4);
    bf16x8 r;
    r[0] = f2bf(a.x); r[1] = f2bf(a.y); r[2] = f2bf(a.z); r[3] = f2bf(a.w);
    r[4] = f2bf(c.x); r[5] = f2bf(c.y); r[6] = f2bf(c.z); r[7] = f2bf(c.w);
    *(bf16x8*)(Wb + (size_t)idx * 8) = r;
}

#define LOADB(dst, kb_) do {                                                   \
    _Pragma("unroll")                                                          \
    for (int n = 0; n < 5; ++n)                                                \
        dst[n] = *(const bf16x8*)(Wb + boff[n] + (kb_) * 512);                 \
    } while (0)

#define DOMFMA(src, kb_) do {                                                  \
    const bf16x8 a_ = *(const bf16x8*)&xs[rbase + l15][(kb_) * 32 + l4 * 8];   \
    _Pragma("unroll")                                                          \
    for (int n = 0; n < 5; ++n)                                                \
        acc[n] = __builtin_amdgcn_mfma_f32_16x16x32_bf16(a_, src[n], acc[n], 0, 0, 0); \
    } while (0)

// ---------------- fused bf16-MFMA GEMM + argmax + softmax + fp32 refine + gather ----------------
// grid 512 = 256 M-tiles x 2 N-halves; 512 threads = 8 waves; 2 blocks/CU -> 16 waves/CU.
// Block: rows [mt*32,+32) x cols [h*320,+320) (one group). Wave w: rows (w>>2)*16..+16,
// col-chunk (w&3)*80. No global atomics; per-block partials.
__global__ __launch_bounds__(512, 4) void fused_vq_k(
    const float* __restrict__ x, const short* __restrict__ Wb,
    const float* __restrict__ W, const float* __restrict__ b,
    const float* __restrict__ codebook,
    float* __restrict__ partials,   // [NBLK][640]: counts(320) then probs(320)
    float* __restrict__ xq) {

    __shared__ short xs[BM][XS_STRIDE];      // 49664 B
    __shared__ float pacc[2][VSZ];
    __shared__ float cnt_f[VSZ];
    __shared__ float wmax[BM][4];
    __shared__ int   warg[BM][4];
    __shared__ float ssum[BM][4];
    __shared__ float rmax_s[BM];
    __shared__ int   rarg_s[BM];
    __shared__ int   cnt_s[BM];
    __shared__ int   list_s[BM][16];
    __shared__ int   code_s[BM];
    __shared__ int   work_s[BM];
    __shared__ int   nwork_s;

    const int tid   = threadIdx.x;
    const int lane  = tid & 63;
    const int w     = tid >> 6;       // wave 0..7
    const int l15   = lane & 15;
    const int l4    = lane >> 4;      // 0..3
    const int mt    = (int)blockIdx.x >> 1;
    const int h     = (int)blockIdx.x & 1;      // N-half = group
    const int row0  = mt * BM;
    const int rbase = (w >> 2) * 16;  // wave's 16-row half
    const int nf0   = h * 20 + (w & 3) * 5;     // wave's first 16-col frag

    for (int i = tid; i < VSZ; i += 512) cnt_f[i] = 0.f;
    if (tid < BM) cnt_s[tid] = 0;
    if (tid == 0) nwork_s = 0;

    // ---- stage x tile as bf16: 32 rows x 768 k ----
    {
        const int srow = tid >> 4;
        const int sk   = (tid & 15) * 4;
        const float* xp = x + (size_t)(row0 + srow) * KDIM + sk;
#pragma unroll
        for (int t = 0; t < 12; ++t) {
            const float4 v = *(const float4*)(xp + t * 64);
            const short t0 = f2bf(v.x), t1 = f2bf(v.y), t2 = f2bf(v.z), t3 = f2bf(v.w);
            const int lo = (t0 & 0xffff) | (t1 << 16);
            const int hi = (t2 & 0xffff) | (t3 << 16);
            *(int2*)&xs[srow][t * 64 + sk] = make_int2(lo, hi);
        }
    }

    // packed-B offsets (shorts): frag (nf0+n, kb) at ((nf0+n)*1536 + lane)*8 + kb*512
    int boff[5];
#pragma unroll
    for (int n = 0; n < 5; ++n) boff[n] = ((nf0 + n) * 1536 + lane) * 8;

    f32x4 acc[5];
#pragma unroll
    for (int n = 0; n < 5; ++n) acc[n] = (f32x4){0.f, 0.f, 0.f, 0.f};

    bf16x8 c0[5], c1[5];
    LOADB(c0, 0);
    LOADB(c1, 1);

    __syncthreads();   // x tile ready

#pragma unroll
    for (int kb = 0; kb < NKB; kb += 2) {
        DOMFMA(c0, kb);
        if (kb + 2 < NKB) LOADB(c0, kb + 2);
        DOMFMA(c1, kb + 1);
        if (kb + 3 < NKB) LOADB(c1, kb + 3);
    }

    // bias (zeros in this problem, kept exact)
#pragma unroll
    for (int n = 0; n < 5; ++n) {
        const float bv = b[(nf0 + n) * 16 + l15];
#pragma unroll
        for (int r = 0; r < 4; ++r) acc[n][r] += bv;
    }

    // E1: wave-local per-row max/argmax over this wave's 80 cols
    // rows: rbase + l4*4 + r ; cols: (nf0+n)*16 + l15
    float m4[4]; int a4[4];
#pragma unroll
    for (int r = 0; r < 4; ++r) { m4[r] = -3.4e38f; a4[r] = 0x7fffffff; }
#pragma unroll
    for (int n = 0; n < 5; ++n) {
        const int col = (nf0 + n) * 16 + l15;
#pragma unroll
        for (int r = 0; r < 4; ++r) {
            const float v = acc[n][r];
            if (v > m4[r]) { m4[r] = v; a4[r] = col; }
        }
    }
#pragma unroll
    for (int off = 8; off >= 1; off >>= 1)
#pragma unroll
        for (int r = 0; r < 4; ++r) {
            const float om = __shfl_xor(m4[r], off);
            const int   oa = __shfl_xor(a4[r], off);
            if (om > m4[r] || (om == m4[r] && oa < a4[r])) { m4[r] = om; a4[r] = oa; }
        }
    if (l15 == 0)
#pragma unroll
        for (int r = 0; r < 4; ++r) {
            const int row = rbase + l4 * 4 + r;
            wmax[row][w & 3] = m4[r];
            warg[row][w & 3] = a4[r];
        }
    __syncthreads();

    // E2a: combine 4 col-chunks -> row max over 320
    if (tid < BM) {
        float m = -3.4e38f; int c = 0x7fffffff;
#pragma unroll
        for (int q = 0; q < 4; ++q) {
            const float mq = wmax[tid][q];
            const int   cq = warg[tid][q];
            if (mq > m || (mq == m && cq < c)) { m = mq; c = cq; }
        }
        rmax_s[tid] = m;
        rarg_s[tid] = c;
    }
    __syncthreads();

    // E2b: candidate scan + exp + denominator partials
    float rm[4];
#pragma unroll
    for (int r = 0; r < 4; ++r) rm[r] = rmax_s[rbase + l4 * 4 + r];
    float sden[4] = {0.f, 0.f, 0.f, 0.f};
#pragma unroll
    for (int n = 0; n < 5; ++n) {
        const int col = (nf0 + n) * 16 + l15;
#pragma unroll
        for (int r = 0; r < 4; ++r) {
            const float v = acc[n][r];
            if (v > rm[r] - MARGIN) {
                const int row = rbase + l4 * 4 + r;
                const int idx = atomicAdd(&cnt_s[row], 1);
                if (idx < 16) list_s[row][idx] = col;
            }
            const float e = __expf(v - rm[r]);
            acc[n][r] = e;
            sden[r] += e;
        }
    }
#pragma unroll
    for (int off = 8; off >= 1; off >>= 1)
#pragma unroll
        for (int r = 0; r < 4; ++r) sden[r] += __shfl_xor(sden[r], off);
    if (l15 == 0)
#pragma unroll
        for (int r = 0; r < 4; ++r) ssum[rbase + l4 * 4 + r][w & 3] = sden[r];
    __syncthreads();

    // E3: single-candidate fast path; multi-candidate -> worklist
    if (tid < BM) {
        if (cnt_s[tid] <= 1) {
            code_s[tid] = rarg_s[tid];
        } else {
            const int wi = atomicAdd(&nwork_s, 1);
            work_s[wi] = tid;
        }
    }

    // E5: softmax column sums -> pacc[half][v] (plain stores, col owned by one wave per half)
    float inv[4];
#pragma unroll
    for (int r = 0; r < 4; ++r) {
        const int row = rbase + l4 * 4 + r;
        inv[r] = 1.f / (ssum[row][0] + ssum[row][1] + ssum[row][2] + ssum[row][3]);
    }
#pragma unroll
    for (int n = 0; n < 5; ++n) {
        float pc = 0.f;
#pragma unroll
        for (int r = 0; r < 4; ++r) pc += acc[n][r] * inv[r];
        pc += __shfl_xor(pc, 16);
        pc += __shfl_xor(pc, 32);
        if (l4 == 0) pacc[w >> 2][(nf0 + n) * 16 + l15 - h * VSZ] = pc;
    }
    __syncthreads();

    // E4: fp32-exact refinement, one wave per pending row
    const int nwork = nwork_s;
    for (int it = w; it < nwork; it += 8) {
        const int row  = work_s[it];
        const int grow = row0 + row;
        const int nc   = min(cnt_s[row], 16);
        float bestv = -3.4e38f; int bestc = 0x7fffffff;
        for (int ci = 0; ci < nc; ++ci) {
            const int col = list_s[row][ci];
            float p = 0.f;
            for (int j = lane; j < KDIM; j += 64)
                p += x[(size_t)grow * KDIM + j] * W[(size_t)col * KDIM + j];
#pragma unroll
            for (int off = 32; off >= 1; off >>= 1) p += __shfl_xor(p, off);
            p += b[col];
            if (p > bestv || (p == bestv && col < bestc)) { bestv = p; bestc = col; }
        }
        if (lane == 0) code_s[row] = bestc;
    }
    __syncthreads();

    // counts histogram in LDS
    if (tid < BM) atomicAdd(&cnt_f[code_s[tid] - h * VSZ], 1.f);

    // E7: gather xq for this block's 32 rows, its group's 128-dim half
#pragma unroll
    for (int u = 0; u < 2; ++u) {
        const int f   = tid + u * 512;      // float4 index 0..1023
        const int row = f >> 5;
        const int d4  = (f & 31) * 4;
        const int k   = code_s[row];        // global col = g*320+v = codebook row
        const float4 v = *(const float4*)(codebook + (size_t)k * DSZ + d4);
        *(float4*)(xq + (size_t)(row0 + row) * (GSZ * DSZ) + h * DSZ + d4) = v;
    }
    __syncthreads();

    // per-block partials: counts(320) then probs(320), coalesced
    float* myp = partials + (size_t)blockIdx.x * NCOL;
    for (int i = tid; i < NCOL; i += 512)
        myp[i] = (i < VSZ) ? cnt_f[i] : (pacc[0][i - VSZ] + pacc[1][i - VSZ]);
}

// ---------------- reduce partials over the 256 M-tiles of each group ----------------
// accf[0..639] = counts, accf[640..1279] = probs
__global__ __launch_bounds__(256) void reduce_k(const float* __restrict__ partials,
                                                float* __restrict__ accf) {
    const int c   = blockIdx.x * 256 + threadIdx.x;   // 0..1279
    const int isp = c >= NCOL;
    const int cc  = isp ? c - NCOL : c;
    const int g   = cc / VSZ;
    const int v   = cc - g * VSZ;
    const float* base = partials + (size_t)g * NCOL + (isp ? VSZ + v : v);
    float s = 0.f;
#pragma unroll 8
    for (int m = 0; m < NMT; ++m) s += base[(size_t)m * (2 * NCOL)];
    accf[c] = s;
}

// ---------------- perplexities + constant ----------------
__global__ __launch_bounds__(640) void finalize_k(
    const float* __restrict__ counts, const float* __restrict__ probs,
    float* __restrict__ out_scalars) {
    __shared__ float se_c[GSZ], se_p[GSZ];
    const int t = threadIdx.x;
    if (t < GSZ) { se_c[t] = 0.f; se_p[t] = 0.f; }
    __syncthreads();
    const int g = t / VSZ;
    const float hp = counts[t] * (1.f / (float)NROWS);
    const float ap = probs[t]  * (1.f / (float)NROWS);
    float tc = hp * logf(hp + 1e-7f);
    float tp = ap * logf(ap + 1e-7f);
#pragma unroll
    for (int off = 32; off >= 1; off >>= 1) {
        tc += __shfl_xor(tc, off);
        tp += __shfl_xor(tp, off);
    }
    if ((t & 63) == 0) { atomicAdd(&se_c[g], tc); atomicAdd(&se_p[g], tp); }
    __syncthreads();
    if (t == 0) {
        out_scalars[0] = (float)NCOL;
        out_scalars[1] = expf(-se_c[0]) + expf(-se_c[1]);
        out_scalars[2] = expf(-se_p[0]) + expf(-se_p[1]);
    }
}

extern "C" void kernel_launch(void* const* d_in, const int* in_sizes, int n_in,
                              void* d_out, int out_size, void* d_ws, size_t ws_size,
                              hipStream_t stream) {
    const float* x        = (const float*)d_in[0];
    const float* W        = (const float*)d_in[1];
    const float* b        = (const float*)d_in[2];
    const float* codebook = (const float*)d_in[3];
    float* out = (float*)d_out;

    short* Wb       = (short*)d_ws;                                   // 983040 B
    float* partials = (float*)((char*)d_ws + 983040);                 // 512*640*4 = 1310720 B
    float* accf     = (float*)((char*)d_ws + 983040 + 1310720);       // 1280*4 B

    prep_w_k<<<dim3(120), dim3(512), 0, stream>>>(W, Wb);
    fused_vq_k<<<dim3(NBLK), dim3(512), 0, stream>>>(x, Wb, W, b, codebook,
                                                     partials, out);
    reduce_k<<<dim3(5), dim3(256), 0, stream>>>(partials, accf);
    finalize_k<<<dim3(1), dim3(640), 0, stream>>>(accf, accf + NCOL, out + XQ_TOTAL);
}